// Round 10
// baseline (49.675 us; speedup 1.0000x reference)
//
#include <hip/hip_runtime.h>

#define NUM_SLICE 32

// Problem constants (fixed by setup_inputs)
constexpr int Bc = 8;
constexpr int Cc = 128;
constexpr int Nc = 65536;

// Tiling: constant-occupancy curve (2048 blocks, 8/CU, 32 waves/CU).
// Stream-count trend: 128->16->8->4 streams/block = 72.5->60.9->53.3->48.5us.
// R9 probes CPB=2/CHUNK=16384 (2 streams x 64KB per block).
constexpr int CPB     = 2;     // channels per block
constexpr int CHUNK   = 16384; // points (n) per block
constexpr int THREADS = 256;
constexpr int PTS_PER_ITER = THREADS * 4;      // 1024 points / iter (float4)
constexpr int NITER   = CHUNK / PTS_PER_ITER;  // 16
constexpr int ACC_LD  = 33;    // padded stride: bank(c*33+s) = (c+s)%32
constexpr int NREP    = 2;     // replicas by lane parity: halves same-addr passes

typedef float f32x4 __attribute__((ext_vector_type(4)));
typedef int   i32x4 __attribute__((ext_vector_type(4)));

__global__ __launch_bounds__(THREADS) void init_out_kernel(float* out, int n) {
    int i = blockIdx.x * blockDim.x + threadIdx.x;
    if (i < n) out[i] = 0.0f;
}

__global__ __launch_bounds__(THREADS) void slice_pool_kernel(
    const float* __restrict__ in,       // [B, C, N]
    const int*   __restrict__ idx,      // [B, N], values in [0, 32)
    unsigned int* __restrict__ out)     // [B, C, 32] as uint bits (all >= 0)
{
    __shared__ unsigned int acc[NREP][CPB * ACC_LD];

    const int t = threadIdx.x;
    for (int i = t; i < NREP * CPB * ACC_LD; i += THREADS)
        (&acc[0][0])[i] = 0u;
    __syncthreads();

    const int chunk = blockIdx.x;           // 0..3
    const int cg    = blockIdx.y;           // 0..63
    const int b     = blockIdx.z;           // 0..7
    const int c0    = cg * CPB;
    const int n0    = chunk * CHUNK;
    const int rep   = t & 1;                // lane-parity replica

    const i32x4* __restrict__ idx4   = (const i32x4*)(idx + (size_t)b * Nc + n0);
    const float* __restrict__ inbase = in + ((size_t)b * Cc + c0) * Nc + n0;

    unsigned int* __restrict__ accr = acc[rep];

    #pragma unroll 2
    for (int p = 0; p < NITER; ++p) {
        const int e    = p * THREADS + t;  // int4 slot within chunk
        const i32x4 iv = idx4[e];          // L2-served (re-read established free)
        const int off  = e * 4;            // element offset within chunk
        #pragma unroll
        for (int c = 0; c < CPB; ++c) {
            const f32x4 v = *(const f32x4*)(inbase + (size_t)c * Nc + off);
            const int base = c * ACC_LD;
            // fmax(x,0) == 0 bits iff x <= 0: those atomics are no-ops vs the
            // zero-initialized accumulator -> skip (halves active lanes).
            const unsigned int bx = __float_as_uint(fmaxf(v[0], 0.0f));
            const unsigned int by = __float_as_uint(fmaxf(v[1], 0.0f));
            const unsigned int bz = __float_as_uint(fmaxf(v[2], 0.0f));
            const unsigned int bw = __float_as_uint(fmaxf(v[3], 0.0f));
            if (bx) atomicMax(&accr[base + iv[0]], bx);
            if (by) atomicMax(&accr[base + iv[1]], by);
            if (bz) atomicMax(&accr[base + iv[2]], bz);
            if (bw) atomicMax(&accr[base + iv[3]], bw);
        }
    }
    __syncthreads();

    // Epilogue: one thread per (channel, slice); merge replicas -> global max
    if (t < CPB * NUM_SLICE) {
        const int c = t >> 5;
        const int s = t & 31;
        unsigned int v = acc[0][c * ACC_LD + s];
        const unsigned int v1 = acc[1][c * ACC_LD + s];
        v = v > v1 ? v : v1;
        if (v != 0u) {
            atomicMax(&out[(((size_t)b * Cc) + c0 + c) * NUM_SLICE + s], v);
        }
    }
}

extern "C" void kernel_launch(void* const* d_in, const int* in_sizes, int n_in,
                              void* d_out, int out_size, void* d_ws, size_t ws_size,
                              hipStream_t stream) {
    const float* in  = (const float*)d_in[0];   // [8,128,65536,1] f32
    const int*   idx = (const int*)  d_in[1];   // [8,65536] i32
    float* out = (float*)d_out;                 // [8,128,32,1] f32

    // Zero the output every launch (harness poisons d_out, never re-poisons).
    const int n_out = Bc * Cc * NUM_SLICE;      // 32768
    init_out_kernel<<<(n_out + THREADS - 1) / THREADS, THREADS, 0, stream>>>(out, n_out);

    dim3 grid(Nc / CHUNK, Cc / CPB, Bc);        // (4, 64, 8) = 2048 blocks
    slice_pool_kernel<<<grid, THREADS, 0, stream>>>(in, idx, (unsigned int*)out);
}

// Round 11
// 45.927 us; speedup vs baseline: 1.0816x; 1.0816x over previous
//
#include <hip/hip_runtime.h>

#define NUM_SLICE 32

// Problem constants (fixed by setup_inputs)
constexpr int Bc = 8;
constexpr int Cc = 128;
constexpr int Nc = 65536;

// R10: exclusive-ownership tiling. Each block owns 2 channels x ALL 64K
// points, so it computes final maxima for its 64 outputs and plain-stores
// them: no init kernel, no global atomics, ONE dispatch.
// Grid (64, 8) = 512 blocks x 1024 thr = 2 blocks/CU = 32 waves/CU.
constexpr int CPB     = 2;     // channels per block (full rows)
constexpr int THREADS = 1024;
constexpr int PTS_PER_ITER = THREADS * 4;      // 4096 points / iter (float4)
constexpr int NITER   = Nc / PTS_PER_ITER;     // 16
constexpr int ACC_LD  = 33;    // padded stride: bank(c*33+s) = (c+s)%32
constexpr int NREP    = 2;     // replicas by lane parity: halves same-addr passes

typedef float f32x4 __attribute__((ext_vector_type(4)));
typedef int   i32x4 __attribute__((ext_vector_type(4)));

__global__ __launch_bounds__(THREADS, 8) void slice_pool_kernel(
    const float* __restrict__ in,       // [B, C, N]
    const int*   __restrict__ idx,      // [B, N], values in [0, 32)
    unsigned int* __restrict__ out)     // [B, C, 32] as uint bits (all >= 0)
{
    __shared__ unsigned int acc[NREP][CPB * ACC_LD];

    const int t = threadIdx.x;
    if (t < NREP * CPB * ACC_LD) (&acc[0][0])[t] = 0u;
    __syncthreads();

    const int cg = blockIdx.x;              // 0..63
    const int b  = blockIdx.y;              // 0..7
    const int c0 = cg * CPB;
    const int rep = t & 1;                  // lane-parity replica

    const i32x4* __restrict__ idx4   = (const i32x4*)(idx + (size_t)b * Nc);
    const float* __restrict__ inbase = in + ((size_t)b * Cc + c0) * Nc;

    unsigned int* __restrict__ accr = acc[rep];

    #pragma unroll 2
    for (int p = 0; p < NITER; ++p) {
        const int e    = p * THREADS + t;  // int4 slot within row
        const i32x4 iv = idx4[e];          // idx row: L2/L3-served re-reads
        const int off  = e * 4;            // element offset within row
        #pragma unroll
        for (int c = 0; c < CPB; ++c) {
            const f32x4 v = *(const f32x4*)(inbase + (size_t)c * Nc + off);
            const int base = c * ACC_LD;
            // fmax(x,0) == 0 bits iff x <= 0: those atomics are no-ops vs the
            // zero-initialized accumulator -> skip (halves active lanes).
            const unsigned int bx = __float_as_uint(fmaxf(v[0], 0.0f));
            const unsigned int by = __float_as_uint(fmaxf(v[1], 0.0f));
            const unsigned int bz = __float_as_uint(fmaxf(v[2], 0.0f));
            const unsigned int bw = __float_as_uint(fmaxf(v[3], 0.0f));
            if (bx) atomicMax(&accr[base + iv[0]], bx);
            if (by) atomicMax(&accr[base + iv[1]], by);
            if (bz) atomicMax(&accr[base + iv[2]], bz);
            if (bw) atomicMax(&accr[base + iv[3]], bw);
        }
    }
    __syncthreads();

    // Epilogue: block exclusively owns its 64 outputs -> plain store
    // (unconditional: also overwrites harness poison; empty slice -> 0).
    if (t < CPB * NUM_SLICE) {
        const int c = t >> 5;
        const int s = t & 31;
        unsigned int v = acc[0][c * ACC_LD + s];
        const unsigned int v1 = acc[1][c * ACC_LD + s];
        v = v > v1 ? v : v1;
        out[(((size_t)b * Cc) + c0 + c) * NUM_SLICE + s] = v;
    }
}

extern "C" void kernel_launch(void* const* d_in, const int* in_sizes, int n_in,
                              void* d_out, int out_size, void* d_ws, size_t ws_size,
                              hipStream_t stream) {
    const float* in  = (const float*)d_in[0];   // [8,128,65536,1] f32
    const int*   idx = (const int*)  d_in[1];   // [8,65536] i32
    unsigned int* out = (unsigned int*)d_out;   // [8,128,32,1] f32 (>=0 bits)

    dim3 grid(Cc / CPB, Bc);                    // (64, 8) = 512 blocks
    slice_pool_kernel<<<grid, THREADS, 0, stream>>>(in, idx, out);
}